// Round 1
// baseline (1943.716 us; speedup 1.0000x reference)
//
#include <hip/hip_runtime.h>

// MultiSpectralDCTLayer: Y = W @ X @ W^T per (b,c) tile, then radial band mask.
// Mask bug (bitwise XOR) => only groups c=0 (s<196) and c=1 (s>=196) keep any
// entries, where s = (i^2)+(j^2) with ^ = XOR. Groups 2..63 are constant 1e-8.
// => 3968/4096 tiles are pure fills; 128 tiles need the DCT.

#define SIZE   112
#define TILE   (SIZE * SIZE)   // 12544 floats per (b,c) tile
#define TILE4  (TILE / 4)      // 3136 float4s
#define ROW4   (SIZE / 4)      // 28

__global__ __launch_bounds__(256)
void dct_band_kernel(const float* __restrict__ x,
                     const float* __restrict__ W,
                     float* __restrict__ out)
{
    const int blk = blockIdx.x;       // b*64 + c
    const int c   = blk & 63;
    const int tid = threadIdx.x;
    float* outTile = out + (size_t)blk * TILE;

    __shared__ float U[TILE];         // 50176 B: U = W @ X (compute path only)

    if (c >= 2) {
        // ---- pure fill: every entry is 1e-8 ----
        const float4 v = make_float4(1e-8f, 1e-8f, 1e-8f, 1e-8f);
        float4* o4 = (float4*)outTile;
        #pragma unroll
        for (int n = 0; n < 13; ++n) {
            int idx = tid + n * 256;
            if (idx < TILE4) o4[idx] = v;
        }
        return;
    }

    // ---- compute path: Y = W @ X @ W^T, then mask ----
    const float* xTile = x + (size_t)blk * TILE;

    // Stage A: U[i][l] = sum_k W[i][k] * X[k][l]
    // Each thread owns 4 consecutive l for a fixed i (float4-coalesced X reads,
    // wave-broadcast W[i][k] reads).
    for (int n = 0; n < 13; ++n) {
        int e4 = tid + n * 256;
        if (e4 >= TILE4) break;
        int i  = e4 / ROW4;
        int l4 = e4 % ROW4;
        const float* wrow = W + i * SIZE;
        float4 acc = make_float4(0.f, 0.f, 0.f, 0.f);
        for (int k = 0; k < SIZE; ++k) {
            float  wk = wrow[k];
            float4 xv = ((const float4*)(xTile + k * SIZE))[l4];
            acc.x += wk * xv.x;
            acc.y += wk * xv.y;
            acc.z += wk * xv.z;
            acc.w += wk * xv.w;
        }
        ((float4*)U)[e4] = acc;   // flat offset e4*4 == i*112 + l4*4
    }
    __syncthreads();

    // Stage B: Y[i][j] = sum_l U[i][l] * W[j][l]
    // Each thread owns 4 consecutive j for a fixed i (LDS-broadcast U reads,
    // L1-resident column-walk W reads, float4-coalesced Y writes).
    for (int n = 0; n < 13; ++n) {
        int e4 = tid + n * 256;
        if (e4 >= TILE4) continue;
        int i  = e4 / ROW4;
        int j4 = e4 % ROW4;
        int j0 = j4 * 4;
        const float* urow = U + i * SIZE;
        const float* w0 = W + (j0 + 0) * SIZE;
        const float* w1 = W + (j0 + 1) * SIZE;
        const float* w2 = W + (j0 + 2) * SIZE;
        const float* w3 = W + (j0 + 3) * SIZE;
        float4 acc = make_float4(0.f, 0.f, 0.f, 0.f);
        for (int l = 0; l < SIZE; ++l) {
            float u = urow[l];
            acc.x += u * w0[l];
            acc.y += u * w1[l];
            acc.z += u * w2[l];
            acc.w += u * w3[l];
        }
        // Mask: s = (i^2)+(j^2) (bitwise XOR — faithful to source bug).
        // c==0 keeps s<196 ; c==1 keeps s>=196 ; else 1e-8 (handled above).
        const int  xi  = i ^ 2;
        const bool g1  = (c != 0);
        int s0 = xi + ((j0 + 0) ^ 2);
        int s1 = xi + ((j0 + 1) ^ 2);
        int s2 = xi + ((j0 + 2) ^ 2);
        int s3 = xi + ((j0 + 3) ^ 2);
        float4 res;
        res.x = ((s0 < 196) != g1) ? acc.x : 1e-8f;
        res.y = ((s1 < 196) != g1) ? acc.y : 1e-8f;
        res.z = ((s2 < 196) != g1) ? acc.z : 1e-8f;
        res.w = ((s3 < 196) != g1) ? acc.w : 1e-8f;
        ((float4*)outTile)[e4] = res;
    }
}

extern "C" void kernel_launch(void* const* d_in, const int* in_sizes, int n_in,
                              void* d_out, int out_size, void* d_ws, size_t ws_size,
                              hipStream_t stream) {
    const float* x = (const float*)d_in[0];
    const float* W = (const float*)d_in[1];
    float* out = (float*)d_out;
    (void)in_sizes; (void)n_in; (void)out_size; (void)d_ws; (void)ws_size;
    dct_band_kernel<<<dim3(64 * 64), dim3(256), 0, stream>>>(x, W, out);
}

// Round 2
// 315.246 us; speedup vs baseline: 6.1657x; 6.1657x over previous
//
#include <hip/hip_runtime.h>

// MultiSpectralDCTLayer: Y = W @ X @ W^T per (b,c) tile, then radial band mask.
// XOR bug in the mask => only c=0 (s<196) and c=1 (s>=196) keep entries, where
// s = (i^2)+(j^2) with ^ = bitwise XOR. Groups 2..63 are constant 1e-8.
//
// Grid layout: 512 compute blocks first (128 tiles x 4 row-chunks of 28 rows),
// then 3968 pure-fill blocks. One kernel so fill writes overlap compute.
// LDS 64512 B -> 2 blocks/CU.

#define SIZE  112
#define TILE  (SIZE * SIZE)    // 12544
#define TILE4 (TILE / 4)       // 3136
#define NCOMPUTE 512
#define FILLV 1e-8f

#define DOT4(a, b) ((a).x*(b).x + (a).y*(b).y + (a).z*(b).z + (a).w*(b).w)

__global__ __launch_bounds__(256)
void dct_band_kernel(const float* __restrict__ x,
                     const float* __restrict__ W,
                     float* __restrict__ out)
{
    const int tid = threadIdx.x;
    const int blk = blockIdx.x;

    if (blk >= NCOMPUTE) {
        // ---- pure fill: groups c>=2 are 1e-8 everywhere ----
        const int f = blk - NCOMPUTE;
        const int b = f / 62;
        const int c = 2 + f % 62;
        float4* o4 = (float4*)(out + (size_t)(b * 64 + c) * TILE);
        const float4 v = make_float4(FILLV, FILLV, FILLV, FILLV);
        #pragma unroll
        for (int n = 0; n < 13; ++n) {
            int e = tid + n * 256;
            if (e < TILE4) o4[e] = v;
        }
        return;
    }

    // ---- compute path ----
    // regA: phase 1 = Xs[k][l4] (row stride 28 float4s, 3136 used)
    //       phase 3 = Wb[jq*113 + m*28 + l4] = W[4*jq+m][4*l4..4*l4+3] (3164 used)
    __shared__ float4 regA[3248];   // 51968 B
    __shared__ float4 Usm[784];     // U[di][l4], row stride 28 float4s; 12544 B

    const int q  = blk & 3;          // row chunk: rows i0..i0+27
    const int t  = blk >> 2;         // tile 0..127
    const int b  = t >> 1;
    const int c  = t & 1;
    const int i0 = 28 * q;
    const size_t tOff = (size_t)(b * 64 + c) * TILE;

    // phase 1: X tile -> LDS (coalesced float4)
    const float4* x4 = (const float4*)(x + tOff);
    #pragma unroll
    for (int n = 0; n < 13; ++n) {
        int e = tid + n * 256;
        if (e < TILE4) regA[e] = x4[e];
    }
    __syncthreads();

    // phase 2 (stage A): U[i0+di][l] = sum_k W[i0+di][k] * X[k][l]
    // thread = (diq, l4): 4 di rows x 4 l cols; 7*28 = 196 active threads.
    if (tid < 196) {
        const int diq = tid / 28;
        const int l4  = tid % 28;
        float4 u0 = make_float4(0,0,0,0), u1 = u0, u2 = u0, u3 = u0;
        const float* wr0 = W + (i0 + 4 * diq) * SIZE;
        const float* wr1 = wr0 + SIZE;
        const float* wr2 = wr1 + SIZE;
        const float* wr3 = wr2 + SIZE;
        #pragma unroll 4
        for (int k = 0; k < SIZE; ++k) {
            float4 xv = regA[k * 28 + l4];      // LDS, contiguous/broadcast
            float w0 = wr0[k], w1 = wr1[k], w2 = wr2[k], w3 = wr3[k]; // L1 broadcast
            u0.x += w0 * xv.x; u0.y += w0 * xv.y; u0.z += w0 * xv.z; u0.w += w0 * xv.w;
            u1.x += w1 * xv.x; u1.y += w1 * xv.y; u1.z += w1 * xv.z; u1.w += w1 * xv.w;
            u2.x += w2 * xv.x; u2.y += w2 * xv.y; u2.z += w2 * xv.z; u2.w += w2 * xv.w;
            u3.x += w3 * xv.x; u3.y += w3 * xv.y; u3.z += w3 * xv.z; u3.w += w3 * xv.w;
        }
        const int ub = 4 * diq * 28 + l4;
        Usm[ub]          = u0;
        Usm[ub + 28]     = u1;
        Usm[ub + 56]     = u2;
        Usm[ub + 84]     = u3;
    }
    __syncthreads();  // all Xs reads done, U complete

    // phase 3: W -> LDS in quad-row-swizzled padded layout (overwrites Xs)
    const float4* W4 = (const float4*)W;
    #pragma unroll
    for (int n = 0; n < 13; ++n) {
        int e = tid + n * 256;
        if (e < TILE4) {
            int j = e / 28;              // W row
            int p = e % 28;              // l4
            regA[(j >> 2) * 113 + (j & 3) * 28 + p] = W4[e];
        }
    }
    __syncthreads();

    // phase 4 (stage B): Y[i][j] = sum_l U[i][l] * W[j][l], then mask + store
    if (tid < 196) {
        const int dq = tid / 28;         // di quad 0..6
        const int jq = tid % 28;         // j quad 0..27
        float acc[4][4];
        #pragma unroll
        for (int a = 0; a < 4; ++a)
            #pragma unroll
            for (int d = 0; d < 4; ++d) acc[a][d] = 0.f;

        const float4* Ur = Usm + 4 * dq * 28;
        const float4* Wb = regA + jq * 113;
        #pragma unroll 2
        for (int l = 0; l < 28; ++l) {
            float4 u0 = Ur[l], u1 = Ur[l + 28], u2 = Ur[l + 56], u3 = Ur[l + 84];
            float4 w0 = Wb[l], w1 = Wb[l + 28], w2 = Wb[l + 56], w3 = Wb[l + 84];
            acc[0][0] += DOT4(u0, w0); acc[0][1] += DOT4(u0, w1);
            acc[0][2] += DOT4(u0, w2); acc[0][3] += DOT4(u0, w3);
            acc[1][0] += DOT4(u1, w0); acc[1][1] += DOT4(u1, w1);
            acc[1][2] += DOT4(u1, w2); acc[1][3] += DOT4(u1, w3);
            acc[2][0] += DOT4(u2, w0); acc[2][1] += DOT4(u2, w1);
            acc[2][2] += DOT4(u2, w2); acc[2][3] += DOT4(u2, w3);
            acc[3][0] += DOT4(u3, w0); acc[3][1] += DOT4(u3, w1);
            acc[3][2] += DOT4(u3, w2); acc[3][3] += DOT4(u3, w3);
        }

        const int j0 = 4 * jq;
        const bool g1 = (c != 0);
        #pragma unroll
        for (int mi = 0; mi < 4; ++mi) {
            const int i  = i0 + 4 * dq + mi;
            const int xi = i ^ 2;
            float4 res;
            res.x = (((xi + ((j0 + 0) ^ 2)) < 196) != g1) ? acc[mi][0] : FILLV;
            res.y = (((xi + ((j0 + 1) ^ 2)) < 196) != g1) ? acc[mi][1] : FILLV;
            res.z = (((xi + ((j0 + 2) ^ 2)) < 196) != g1) ? acc[mi][2] : FILLV;
            res.w = (((xi + ((j0 + 3) ^ 2)) < 196) != g1) ? acc[mi][3] : FILLV;
            ((float4*)(out + tOff + (size_t)i * SIZE))[jq] = res;
        }
    }
}

extern "C" void kernel_launch(void* const* d_in, const int* in_sizes, int n_in,
                              void* d_out, int out_size, void* d_ws, size_t ws_size,
                              hipStream_t stream) {
    const float* x = (const float*)d_in[0];
    const float* W = (const float*)d_in[1];
    float* out = (float*)d_out;
    (void)in_sizes; (void)n_in; (void)out_size; (void)d_ws; (void)ws_size;
    dct_band_kernel<<<dim3(NCOMPUTE + 64 * 62), dim3(256), 0, stream>>>(x, W, out);
}